// Round 6
// baseline (120.041 us; speedup 1.0000x reference)
//
#include <hip/hip_runtime.h>

#define NN 1024
#define FF 7
#define HID 256
#define MLPH 64
#define OUTN 8
#define CATN (MLPH + HID + 8)   // 328

#define FMAGIC 0x9E3779B97F4A7C15ULL
#define SCOPE_AGENT __HIP_MEMORY_SCOPE_AGENT

__device__ __forceinline__ float wave_sum(float v) {
#pragma unroll
    for (int m = 32; m >= 1; m >>= 1) v += __shfl_xor(v, m, 64);
    return v;
}
__device__ __forceinline__ float wave_max(float v) {
#pragma unroll
    for (int m = 32; m >= 1; m >>= 1) v = fmaxf(v, __shfl_xor(v, m, 64));
    return v;
}
__device__ __forceinline__ void st_ag(float* p, float v) {
    __hip_atomic_store(p, v, __ATOMIC_RELAXED, SCOPE_AGENT);
}
__device__ __forceinline__ float ld_ag(const float* p) {
    return __hip_atomic_load(p, __ATOMIC_RELAXED, SCOPE_AGENT);
}

// One kernel, 256 WGs x 512 thr, regular launch. Block (b,jg), b=blk>>3.
// Phase 1: cold-load burst (Wm0 row -> 112 VGPRs, x[b] -> LDS), A-pass -> deg
//          rows (agent stores) + d2-max, MLP-L1, jg==0: spd (kept in LDS) +
//          out-zero. Then ONE release flag-store per block.
// Handshake: spin (capped) until all 8 sibling flags == MAGIC. All cross-block
//          data moves via agent-scope atomics (coherent, no cache invalidates).
// Phase 2: B-pass from still-resident LDS pts, fused h/hsum partial, then
//          per-block projection W2 -> Wfc -> Wp_gcn of the OWN hs-partial
//          (replaces the old E/cE collapse; b2/bfc folded in by jg==0),
//          atomicAdd fan-in to out.
union SU {
    float lxs[NN * FF];               // phase 1: full x[b] (28 KB)
    struct {                          // phase 2 overlay (lxs dead)
        float r0[NN], r1[NN], r2[NN];
        float q0s[128], q1s[128], qws[128];
        float hp[512];
        float yh[512];
        float yv[HID];
        float zv[HID];
        float sx1[MLPH], sxf2[MLPH], sglo[8];
    } p2;
};

__global__ __launch_bounds__(512, 2) void gf(const float* __restrict__ x,
                                             const float* __restrict__ Wm0,
                                             const float* __restrict__ W2,
                                             const float* __restrict__ b2,
                                             const float* __restrict__ Wfc,
                                             const float* __restrict__ bfc,
                                             const float* __restrict__ W1,
                                             const float* __restrict__ b1,
                                             const float* __restrict__ Wg,
                                             const float* __restrict__ bg,
                                             const float* __restrict__ Wm1,
                                             const float* __restrict__ bm1,
                                             const float* __restrict__ Wp,
                                             const float* __restrict__ bp,
                                             const float* __restrict__ bm0,
                                             float* __restrict__ mlp_p,
                                             float* __restrict__ deg,
                                             float* __restrict__ bmaxp,
                                             unsigned long long* __restrict__ flags,
                                             float* __restrict__ out) {
    __shared__ __align__(16) SU u;
    __shared__ __align__(16) float l0[NN];
    __shared__ __align__(16) float l1[NN];
    __shared__ __align__(16) float di[NN];
    __shared__ __align__(16) float s2[NN];
    __shared__ float wred[8];
    __shared__ float sspd;

    int blk = blockIdx.x, tid = threadIdx.x, lane = tid & 63, w = tid >> 6;
    int b = blk >> 3, jg = blk & 7;
    unsigned long long* myflag = &flags[b * 8 + jg];
    // clear own flag at entry (covers a skipped re-poison; coherent store)
    if (tid == 0) __hip_atomic_store(myflag, 0ULL, __ATOMIC_RELAXED, SCOPE_AGENT);

    // ---- phase 1: cold-load burst (everything issued before any wait) ----
    const float4* wr = (const float4*)(Wm0 + (jg * 8 + w) * (NN * FF));
    float4 wreg[28];
#pragma unroll
    for (int t = 0; t < 28; ++t) wreg[t] = wr[t * 64 + lane];
    const float4* xr4 = (const float4*)(x + b * (NN * FF));
    float4 xreg0 = xr4[tid];
    float4 xreg1 = xr4[512 + tid];
    float4 xreg2 = xr4[1024 + tid];
    float4 xreg3;
    if (tid < 256) xreg3 = xr4[1536 + tid];
    float4* lx4 = (float4*)u.lxs;
    lx4[tid] = xreg0;
    lx4[512 + tid] = xreg1;
    lx4[1024 + tid] = xreg2;
    if (tid < 256) lx4[1536 + tid] = xreg3;
    __syncthreads();
    l0[tid] = u.lxs[tid * 7 + 1];       l1[tid] = u.lxs[tid * 7 + 2];
    l0[tid + 512] = u.lxs[(tid + 512) * 7 + 1];
    l1[tid + 512] = u.lxs[(tid + 512) * 7 + 2];
    __syncthreads();
    // ---- A-pass: lane = j-pair, wave = 128-wide k-slice ----
    int jA = jg * 128 + lane, jB = jA + 64;
    float pj0a = l0[jA], pj1a = l1[jA];
    float pj0b = l0[jB], pj1b = l1[jB];
    {
        const float4* v0p = (const float4*)&l0[w * 128];
        const float4* v1p = (const float4*)&l1[w * 128];
        unsigned dA = 0u, dB = 0u;
        float mx = 0.f;
#pragma unroll 4
        for (int g = 0; g < 32; ++g) {
            float4 v0 = v0p[g], v1 = v1p[g];
            float dx, dy, d2a, d2b;
            dx = pj0a - v0.x; dy = pj1a - v1.x; d2a = fmaf(dy, dy, dx * dx);
            dx = pj0b - v0.x; dy = pj1b - v1.x; d2b = fmaf(dy, dy, dx * dx);
            dA += (d2a <= 0.09f); dB += (d2b <= 0.09f);
            mx = fmaxf(mx, fmaxf(d2a, d2b));
            dx = pj0a - v0.y; dy = pj1a - v1.y; d2a = fmaf(dy, dy, dx * dx);
            dx = pj0b - v0.y; dy = pj1b - v1.y; d2b = fmaf(dy, dy, dx * dx);
            dA += (d2a <= 0.09f); dB += (d2b <= 0.09f);
            mx = fmaxf(mx, fmaxf(d2a, d2b));
            dx = pj0a - v0.z; dy = pj1a - v1.z; d2a = fmaf(dy, dy, dx * dx);
            dx = pj0b - v0.z; dy = pj1b - v1.z; d2b = fmaf(dy, dy, dx * dx);
            dA += (d2a <= 0.09f); dB += (d2b <= 0.09f);
            mx = fmaxf(mx, fmaxf(d2a, d2b));
            dx = pj0a - v0.w; dy = pj1a - v1.w; d2a = fmaf(dy, dy, dx * dx);
            dx = pj0b - v0.w; dy = pj1b - v1.w; d2b = fmaf(dy, dy, dx * dx);
            dA += (d2a <= 0.09f); dB += (d2b <= 0.09f);
            mx = fmaxf(mx, fmaxf(d2a, d2b));
        }
        s2[w * 128 + lane] = (float)dA;
        s2[w * 128 + 64 + lane] = (float)dB;
        mx = wave_max(mx);
        if (lane == 0) wred[w] = mx;
    }
    __syncthreads();
    if (tid < 128) {
        float s = 0.f;
#pragma unroll
        for (int kk = 0; kk < 8; ++kk) s += s2[kk * 128 + tid];
        st_ag(&deg[b * NN + jg * 128 + tid], s);
    }
    if (tid == 0) {
        float m = wred[0];
#pragma unroll
        for (int i = 1; i < 8; ++i) m = fmaxf(m, wred[i]);
        st_ag(&bmaxp[b * 8 + jg], m);
    }
    // ---- MLP-L1: wreg (regs) x lxs (LDS) ----
    {
        float4 a4 = {0.f, 0.f, 0.f, 0.f};
#pragma unroll
        for (int t = 0; t < 28; ++t) {
            float4 xv = lx4[t * 64 + lane];
            a4.x = fmaf(wreg[t].x, xv.x, a4.x);
            a4.y = fmaf(wreg[t].y, xv.y, a4.y);
            a4.z = fmaf(wreg[t].z, xv.z, a4.z);
            a4.w = fmaf(wreg[t].w, xv.w, a4.w);
        }
        float s = (a4.x + a4.y) + (a4.z + a4.w);
        s = wave_sum(s);
        if (lane == 0) st_ag(&mlp_p[b * MLPH + jg * 8 + w], s);
    }
    __syncthreads();   // wred (bmax) consumed; safe to reuse
    if (jg == 0) {
        float vx = u.lxs[tid * 7 + 3], vy = u.lxs[tid * 7 + 4];
        float sp = sqrtf(fmaf(vx, vx, vy * vy));
        vx = u.lxs[(tid + 512) * 7 + 3]; vy = u.lxs[(tid + 512) * 7 + 4];
        sp += sqrtf(fmaf(vx, vx, vy * vy));
        sp = wave_sum(sp);
        if (lane == 0) wred[w] = sp;
        if (tid < OUTN) st_ag(&out[b * OUTN + tid], 0.f);
    }
    __syncthreads();
    if (jg == 0 && tid == 0) {
        float s = 0.f;
#pragma unroll
        for (int i = 0; i < 8; ++i) s += wred[i];
        sspd = s;
    }
    // all threads' agent stores are vmcnt-drained by this barrier:
    __syncthreads();
    if (tid == 0)
        __hip_atomic_store(myflag, FMAGIC, __ATOMIC_RELEASE, SCOPE_AGENT);

    // ---- handshake: wait for all 8 siblings of batch b (capped spin) ----
    if (tid < 8) {
        int it = 0;
        while (__hip_atomic_load(&flags[b * 8 + tid], __ATOMIC_RELAXED,
                                 SCOPE_AGENT) != FMAGIC && it < (1 << 20)) {
            __builtin_amdgcn_s_sleep(2);
            ++it;
        }
    }
    __syncthreads();

    // ---- phase 2: B-pass (pts still in LDS) ----
    di[tid]       = 1.0f / sqrtf(ld_ag(&deg[b * NN + tid]));
    di[tid + 512] = 1.0f / sqrtf(ld_ag(&deg[b * NN + tid + 512]));
    __syncthreads();
    float* r0 = u.p2.r0;
    float* r1 = u.p2.r1;
    float* r2 = u.p2.r2;
    {
        const float4* v0p = (const float4*)&l0[w * 128];
        const float4* v1p = (const float4*)&l1[w * 128];
        const float4* vdp = (const float4*)&di[w * 128];
        float a0a = 0.f, a1a = 0.f, asa = 0.f;
        float a0b = 0.f, a1b = 0.f, asb = 0.f;
#pragma unroll 4
        for (int g = 0; g < 32; ++g) {
            float4 v0 = v0p[g], v1 = v1p[g], vd = vdp[g];
            float dx, dy, d2, t;
            dx = pj0a - v0.x; dy = pj1a - v1.x; d2 = fmaf(dy, dy, dx * dx);
            t = (d2 <= 0.09f) ? vd.x : 0.0f;
            a0a = fmaf(t, v0.x, a0a); a1a = fmaf(t, v1.x, a1a); asa += t;
            dx = pj0b - v0.x; dy = pj1b - v1.x; d2 = fmaf(dy, dy, dx * dx);
            t = (d2 <= 0.09f) ? vd.x : 0.0f;
            a0b = fmaf(t, v0.x, a0b); a1b = fmaf(t, v1.x, a1b); asb += t;
            dx = pj0a - v0.y; dy = pj1a - v1.y; d2 = fmaf(dy, dy, dx * dx);
            t = (d2 <= 0.09f) ? vd.y : 0.0f;
            a0a = fmaf(t, v0.y, a0a); a1a = fmaf(t, v1.y, a1a); asa += t;
            dx = pj0b - v0.y; dy = pj1b - v1.y; d2 = fmaf(dy, dy, dx * dx);
            t = (d2 <= 0.09f) ? vd.y : 0.0f;
            a0b = fmaf(t, v0.y, a0b); a1b = fmaf(t, v1.y, a1b); asb += t;
            dx = pj0a - v0.z; dy = pj1a - v1.z; d2 = fmaf(dy, dy, dx * dx);
            t = (d2 <= 0.09f) ? vd.z : 0.0f;
            a0a = fmaf(t, v0.z, a0a); a1a = fmaf(t, v1.z, a1a); asa += t;
            dx = pj0b - v0.z; dy = pj1b - v1.z; d2 = fmaf(dy, dy, dx * dx);
            t = (d2 <= 0.09f) ? vd.z : 0.0f;
            a0b = fmaf(t, v0.z, a0b); a1b = fmaf(t, v1.z, a1b); asb += t;
            dx = pj0a - v0.w; dy = pj1a - v1.w; d2 = fmaf(dy, dy, dx * dx);
            t = (d2 <= 0.09f) ? vd.w : 0.0f;
            a0a = fmaf(t, v0.w, a0a); a1a = fmaf(t, v1.w, a1a); asa += t;
            dx = pj0b - v0.w; dy = pj1b - v1.w; d2 = fmaf(dy, dy, dx * dx);
            t = (d2 <= 0.09f) ? vd.w : 0.0f;
            a0b = fmaf(t, v0.w, a0b); a1b = fmaf(t, v1.w, a1b); asb += t;
        }
        r0[w * 128 + lane] = a0a; r0[w * 128 + 64 + lane] = a0b;
        r1[w * 128 + lane] = a1a; r1[w * 128 + 64 + lane] = a1b;
        r2[w * 128 + lane] = asa; r2[w * 128 + 64 + lane] = asb;
    }
    __syncthreads();
    if (tid < 128) {
        float s0 = 0.f, s1 = 0.f, ss = 0.f;
#pragma unroll
        for (int kk = 0; kk < 8; ++kk) {
            s0 += r0[kk * 128 + tid];
            s1 += r1[kk * 128 + tid];
            ss += r2[kk * 128 + tid];
        }
        float dj = di[jg * 128 + tid];
        u.p2.q0s[tid] = dj * s0;
        u.p2.q1s[tid] = dj * s1;
        u.p2.qws[tid] = dj * ss * (1.0f / NN);
    } else if (jg == 0 && tid < 192) {
        int t2 = tid - 128;
        u.p2.sx1[t2] = fmaxf(ld_ag(&mlp_p[b * MLPH + t2]) + bm0[t2], 0.f);
    }
    __syncthreads();
    {   // fused h + weighted hsum partial over this block's 128 j
        int h = tid & 255, jq = tid >> 8;
        float w10 = W1[2 * h], w11 = W1[2 * h + 1], bb = b1[h];
        const float4* q0v = (const float4*)&u.p2.q0s[jq * 64];
        const float4* q1v = (const float4*)&u.p2.q1s[jq * 64];
        const float4* qwv = (const float4*)&u.p2.qws[jq * 64];
        float acc = 0.f;
#pragma unroll
        for (int g = 0; g < 16; ++g) {
            float4 qa = q0v[g], qb = q1v[g], qw4 = qwv[g];
            acc = fmaf(qw4.x, fmaxf(fmaf(qb.x, w11, fmaf(qa.x, w10, bb)), 0.f), acc);
            acc = fmaf(qw4.y, fmaxf(fmaf(qb.y, w11, fmaf(qa.y, w10, bb)), 0.f), acc);
            acc = fmaf(qw4.z, fmaxf(fmaf(qb.z, w11, fmaf(qa.z, w10, bb)), 0.f), acc);
            acc = fmaf(qw4.w, fmaxf(fmaf(qb.w, w11, fmaf(qa.w, w10, bb)), 0.f), acc);
        }
        u.p2.hp[jq * 256 + h] = acc;
    }
    __syncthreads();
    if (tid < HID) {
        r0[tid] = u.p2.hp[tid] + u.p2.hp[256 + tid];   // v = block's hs partial
    } else if (jg == 0 && tid < HID + MLPH) {
        int t2 = tid - HID;
        float a = bm1[t2];
        const float* wv = Wm1 + t2 * MLPH;
#pragma unroll
        for (int k = 0; k < MLPH; ++k) a = fmaf(wv[k], u.p2.sx1[k], a);
        u.p2.sxf2[t2] = fmaxf(a, 0.f);
    } else if (jg == 0 && tid < HID + MLPH + 8) {
        int t2 = tid - HID - MLPH;
        float mxv = 0.f;
#pragma unroll
        for (int g = 0; g < 8; ++g) mxv = fmaxf(mxv, ld_ag(&bmaxp[b * 8 + g]));
        float avg  = sspd * (1.0f / NN);
        float dens = 1.0f / sqrtf(mxv);
        u.p2.sglo[t2] = fmaxf(fmaf(Wg[t2 * 2], avg, fmaf(Wg[t2 * 2 + 1], dens, bg[t2])), 0.f);
    }
    __syncthreads();
    // ---- per-block projection: y = W2 @ v (+b2 on jg0) ----
    {
        int r = tid >> 1, half = tid & 1;
        const float4* w4 = (const float4*)(W2 + r * HID + half * 128);
        const float4* v4 = (const float4*)&r0[half * 128];
        float acc = 0.f;
#pragma unroll
        for (int t = 0; t < 32; ++t) {
            float4 a = w4[t], vv = v4[t];
            acc = fmaf(a.x, vv.x, acc); acc = fmaf(a.y, vv.y, acc);
            acc = fmaf(a.z, vv.z, acc); acc = fmaf(a.w, vv.w, acc);
        }
        u.p2.yh[tid] = acc;
    }
    __syncthreads();
    if (tid < HID)
        u.p2.yv[tid] = u.p2.yh[2 * tid] + u.p2.yh[2 * tid + 1] + (jg == 0 ? b2[tid] : 0.f);
    __syncthreads();
    // ---- z = Wfc @ y (+bfc on jg0) ----
    {
        int r = tid >> 1, half = tid & 1;
        const float4* w4 = (const float4*)(Wfc + r * HID + half * 128);
        const float4* v4 = (const float4*)&u.p2.yv[half * 128];
        float acc = 0.f;
#pragma unroll
        for (int t = 0; t < 32; ++t) {
            float4 a = w4[t], vv = v4[t];
            acc = fmaf(a.x, vv.x, acc); acc = fmaf(a.y, vv.y, acc);
            acc = fmaf(a.z, vv.z, acc); acc = fmaf(a.w, vv.w, acc);
        }
        u.p2.yh[tid] = acc;
    }
    __syncthreads();
    if (tid < HID)
        u.p2.zv[tid] = u.p2.yh[2 * tid] + u.p2.yh[2 * tid + 1] + (jg == 0 ? bfc[tid] : 0.f);
    __syncthreads();
    // ---- res[o] = Wp_gcn_row_o @ z (+ jg0 extras), atomic fan-in ----
    {
        int o = w, ln = lane;
        const float* wpo = Wp + o * CATN;
        float a = wpo[MLPH + ln] * u.p2.zv[ln];
        a = fmaf(wpo[MLPH + ln + 64],  u.p2.zv[ln + 64],  a);
        a = fmaf(wpo[MLPH + ln + 128], u.p2.zv[ln + 128], a);
        a = fmaf(wpo[MLPH + ln + 192], u.p2.zv[ln + 192], a);
        if (jg == 0) a = fmaf(wpo[ln], u.p2.sxf2[ln], a);
        a = wave_sum(a);
        if (ln == 0) {
            if (jg == 0) {
                const float* wg = wpo + MLPH + HID;
#pragma unroll
                for (int g = 0; g < 8; ++g) a = fmaf(wg[g], u.p2.sglo[g], a);
                a += bp[o];
            }
            atomicAdd(&out[b * OUTN + o], a);
        }
    }
}

extern "C" void kernel_launch(void* const* d_in, const int* in_sizes, int n_in,
                              void* d_out, int out_size, void* d_ws, size_t ws_size,
                              hipStream_t stream) {
    const float* x   = (const float*)d_in[0];
    const float* W1  = (const float*)d_in[1];
    const float* b1  = (const float*)d_in[2];
    const float* W2  = (const float*)d_in[3];
    const float* b2  = (const float*)d_in[4];
    const float* Wfc = (const float*)d_in[5];
    const float* bfc = (const float*)d_in[6];
    const float* Wg  = (const float*)d_in[7];
    const float* bg  = (const float*)d_in[8];
    const float* Wm0 = (const float*)d_in[9];
    const float* bm0 = (const float*)d_in[10];
    const float* Wm1 = (const float*)d_in[11];
    const float* bm1 = (const float*)d_in[12];
    const float* Wp  = (const float*)d_in[13];
    const float* bp  = (const float*)d_in[14];
    float* out = (float*)d_out;
    float* ws  = (float*)d_ws;

    float* deg   = ws;              // 32768
    float* mlp_p = ws + 32768;      // 2048
    float* bmaxp = ws + 34816;      // 256
    unsigned long long* flags = (unsigned long long*)(ws + 35072);  // 256 x u64
    // deg/mlp_p/bmaxp written (agent stores) before read each iteration;
    // flags self-clearing at kernel entry -> no host-side init needed.

    gf<<<256, 512, 0, stream>>>(x, Wm0, W2, b2, Wfc, bfc, W1, b1, Wg, bg,
                                Wm1, bm1, Wp, bp, bm0,
                                mlp_p, deg, bmaxp, flags, out);
}

// Round 7
// 113.948 us; speedup vs baseline: 1.0535x; 1.0535x over previous
//
#include <hip/hip_runtime.h>

#define NN 1024
#define FF 7
#define HID 256
#define MLPH 64
#define OUTN 8
#define CATN (MLPH + HID + 8)   // 328

__device__ __forceinline__ float wave_sum(float v) {
#pragma unroll
    for (int m = 32; m >= 1; m >>= 1) v += __shfl_xor(v, m, 64);
    return v;
}
__device__ __forceinline__ float wave_max(float v) {
#pragma unroll
    for (int m = 32; m >= 1; m >>= 1) v = fmaxf(v, __shfl_xor(v, m, 64));
    return v;
}

// g1: 512 WGs x 512 thr, 2 blocks/CU (4 waves/SIMD — occupancy doubled vs r5).
// Block (b,jq), jq in [0,16): A-pass for 64 j (j = jq*64+lane, wave = 128-k
// slice), cold-load burst (Wm0 HALF-row -> 56 VGPRs/thread, x[b] -> LDS),
// MLP-L1 half-row per wave combined in LDS, jq==0: spd + out-zero + pts
// store for g2, (b in [8,16), jq==15): E/cE collapse.
__global__ __launch_bounds__(512, 4) void g1(const float* __restrict__ x,
                                             const float* __restrict__ Wm0,
                                             const float* __restrict__ W2,
                                             const float* __restrict__ b2,
                                             const float* __restrict__ Wfc,
                                             const float* __restrict__ bfc,
                                             const float* __restrict__ Wp,
                                             float* __restrict__ spd,
                                             float* __restrict__ mlp_p,
                                             float* __restrict__ E,
                                             float* __restrict__ cE,
                                             float* __restrict__ deg,
                                             float* __restrict__ bmaxp,
                                             float* __restrict__ pts0,
                                             float* __restrict__ pts1,
                                             float* __restrict__ out) {
    __shared__ __align__(16) float lxs[NN * FF];   // 28 KB
    __shared__ __align__(16) float l0[NN];
    __shared__ __align__(16) float l1[NN];
    __shared__ __align__(16) float s2[512];        // deg partials / E's hp
    __shared__ float wred[8];
    __shared__ float mred[8];
    __shared__ float eg0[HID], eg1[HID];
    int blk = blockIdx.x, tid = threadIdx.x, lane = tid & 63, w = tid >> 6;
    int b = blk >> 4, jq = blk & 15;

    // ---- cold-load burst: all global loads issued before any wait ----
    int hrow = jq * 4 + (w >> 1), hsel = w & 1;    // wave's MLP half-row
    const float4* wr = (const float4*)(Wm0 + hrow * (NN * FF)) + hsel * 896;
    float4 wreg[14];
#pragma unroll
    for (int t = 0; t < 14; ++t) wreg[t] = wr[t * 64 + lane];
    const float4* xr4 = (const float4*)(x + b * (NN * FF));
    float4 x0 = xr4[tid], x1 = xr4[512 + tid], x2 = xr4[1024 + tid], x3;
    if (tid < 256) x3 = xr4[1536 + tid];
    float4* lx4 = (float4*)lxs;
    lx4[tid] = x0;                     // first wait drains the whole burst
    lx4[512 + tid] = x1;
    lx4[1024 + tid] = x2;
    if (tid < 256) lx4[1536 + tid] = x3;
    __syncthreads();
    l0[tid] = lxs[tid * 7 + 1];        l1[tid] = lxs[tid * 7 + 2];
    l0[tid + 512] = lxs[(tid + 512) * 7 + 1];
    l1[tid + 512] = lxs[(tid + 512) * 7 + 2];
    __syncthreads();
    // ---- A-pass: lane = j, wave = 128-wide k-slice ----
    int j = jq * 64 + lane;
    float pj0 = l0[j], pj1 = l1[j];
    {
        const float4* v0p = (const float4*)&l0[w * 128];
        const float4* v1p = (const float4*)&l1[w * 128];
        unsigned dA = 0u;
        float mx = 0.f;
#pragma unroll 4
        for (int g = 0; g < 32; ++g) {
            float4 v0 = v0p[g], v1 = v1p[g];
            float dx, dy, d2;
            dx = pj0 - v0.x; dy = pj1 - v1.x; d2 = fmaf(dy, dy, dx * dx);
            dA += (d2 <= 0.09f); mx = fmaxf(mx, d2);
            dx = pj0 - v0.y; dy = pj1 - v1.y; d2 = fmaf(dy, dy, dx * dx);
            dA += (d2 <= 0.09f); mx = fmaxf(mx, d2);
            dx = pj0 - v0.z; dy = pj1 - v1.z; d2 = fmaf(dy, dy, dx * dx);
            dA += (d2 <= 0.09f); mx = fmaxf(mx, d2);
            dx = pj0 - v0.w; dy = pj1 - v1.w; d2 = fmaf(dy, dy, dx * dx);
            dA += (d2 <= 0.09f); mx = fmaxf(mx, d2);
        }
        s2[w * 64 + lane] = (float)dA;
        mx = wave_max(mx);
        if (lane == 0) wred[w] = mx;
    }
    __syncthreads();
    if (tid < 64) {
        float s = 0.f;
#pragma unroll
        for (int kk = 0; kk < 8; ++kk) s += s2[kk * 64 + tid];
        deg[b * NN + jq * 64 + tid] = s;
    }
    if (tid == 0) {
        float m = wred[0];
#pragma unroll
        for (int i = 1; i < 8; ++i) m = fmaxf(m, wred[i]);
        bmaxp[b * 16 + jq] = m;
    }
    // ---- MLP-L1 half-row: wreg (regs) x lxs (LDS) ----
    {
        float4 a4 = {0.f, 0.f, 0.f, 0.f};
#pragma unroll
        for (int t = 0; t < 14; ++t) {
            float4 xv = lx4[hsel * 896 + t * 64 + lane];
            a4.x = fmaf(wreg[t].x, xv.x, a4.x);
            a4.y = fmaf(wreg[t].y, xv.y, a4.y);
            a4.z = fmaf(wreg[t].z, xv.z, a4.z);
            a4.w = fmaf(wreg[t].w, xv.w, a4.w);
        }
        float s = (a4.x + a4.y) + (a4.z + a4.w);
        s = wave_sum(s);
        if (lane == 0) mred[w] = s;
    }
    __syncthreads();   // mred complete; wred (bmax) consumed -> reusable
    if ((w & 1) == 0 && lane == 0)
        mlp_p[b * MLPH + hrow] = mred[w] + mred[w + 1];
    if (jq == 0) {
        float vx = lxs[tid * 7 + 3], vy = lxs[tid * 7 + 4];
        float sp = sqrtf(fmaf(vx, vx, vy * vy));
        vx = lxs[(tid + 512) * 7 + 3]; vy = lxs[(tid + 512) * 7 + 4];
        sp += sqrtf(fmaf(vx, vx, vy * vy));
        sp = wave_sum(sp);
        if (lane == 0) wred[w] = sp;
        if (tid < OUTN) out[b * OUTN + tid] = 0.f;
        if (tid < 256) {   // pts -> ws for g2 (coalesced float4)
            ((float4*)(pts0 + b * NN))[tid] = ((float4*)l0)[tid];
            ((float4*)(pts1 + b * NN))[tid] = ((float4*)l1)[tid];
        }
    }
    __syncthreads();
    if (jq == 0 && tid == 0) {
        float s = 0.f;
#pragma unroll
        for (int i = 0; i < 8; ++i) s += wred[i];
        spd[b] = s;
    }
    if (b >= 8 && b < 16 && jq == 15) {   // E/cE collapse (block-uniform guard)
        int o = b - 8;
        int half = tid >> 8, col = tid & 255;
        float* hp = s2;
        if (tid < HID) eg0[tid] = Wp[o * CATN + MLPH + tid];
        __syncthreads();
        {
            float a = 0.f;
            const float* wcol = Wfc + (half * 128) * HID + col;
#pragma unroll 8
            for (int m = 0; m < 128; ++m) a = fmaf(eg0[half * 128 + m], wcol[m * HID], a);
            hp[tid] = a;
        }
        __syncthreads();
        if (tid < HID) eg1[tid] = hp[tid] + hp[tid + 256];
        __syncthreads();
        {
            float e = 0.f;
            const float* wcol = W2 + (half * 128) * HID + col;
#pragma unroll 8
            for (int k = 0; k < 128; ++k) e = fmaf(eg1[half * 128 + k], wcol[k * HID], e);
            hp[tid] = e;
        }
        __syncthreads();
        if (tid < HID) {
            E[o * HID + tid] = hp[tid] + hp[tid + 256];
            float c = fmaf(eg1[tid], b2[tid], eg0[tid] * bfc[tid]);
            c = wave_sum(c);
            if (lane == 0) wred[w] = c;
        }
        __syncthreads();
        if (tid == 0) cE[o] = wred[0] + wred[1] + wred[2] + wred[3];
    }
}

// g2: 512 WGs x 512 thr, 2 blocks/CU. Burst-loads pts/deg (coalesced, L2-hot;
// x dependency gone). B-pass for 64 j + fused h/hsum partial + E-projection +
// atomicAdd fan-in (proven r2-r5). jq==0 folds MLP-L2, global branch, cE, bp.
__global__ __launch_bounds__(512, 4) void g2(const float* __restrict__ pts0,
                                             const float* __restrict__ pts1,
                                             const float* __restrict__ deg,
                                             const float* __restrict__ W1,
                                             const float* __restrict__ b1,
                                             const float* __restrict__ Wg,
                                             const float* __restrict__ bg,
                                             const float* __restrict__ Wm1,
                                             const float* __restrict__ bm1,
                                             const float* __restrict__ Wp,
                                             const float* __restrict__ bp,
                                             const float* __restrict__ bm0,
                                             const float* __restrict__ mlp_p,
                                             const float* __restrict__ bmaxp,
                                             const float* __restrict__ spd,
                                             const float* __restrict__ E,
                                             const float* __restrict__ cE,
                                             float* __restrict__ out) {
    __shared__ __align__(16) float l0[NN];
    __shared__ __align__(16) float l1[NN];
    __shared__ __align__(16) float di[NN];
    __shared__ __align__(16) float r0[512];
    __shared__ __align__(16) float r1[512];
    __shared__ __align__(16) float r2[512];
    __shared__ __align__(16) float q0s[64];
    __shared__ __align__(16) float q1s[64];
    __shared__ __align__(16) float qws[64];
    __shared__ __align__(16) float hp[512];
    __shared__ float sx1[MLPH], sxf2[MLPH], sglo[8];
    int blk = blockIdx.x, tid = threadIdx.x, lane = tid & 63, w = tid >> 6;
    int b = blk >> 4, jq = blk & 15;
    // ---- burst: pts + deg, coalesced float4 (L2-hot from g1) ----
    if (tid < 256) {
        ((float4*)l0)[tid] = ((const float4*)(pts0 + b * NN))[tid];
        ((float4*)di)[tid] = ((const float4*)(deg + b * NN))[tid];
    } else {
        ((float4*)l1)[tid - 256] = ((const float4*)(pts1 + b * NN))[tid - 256];
    }
    __syncthreads();
    di[tid] = 1.0f / sqrtf(di[tid]);           // in-place, 1 writer/elem
    di[tid + 512] = 1.0f / sqrtf(di[tid + 512]);
    __syncthreads();
    // ---- B-pass: lane = j, wave = 128-wide k-slice ----
    int j = jq * 64 + lane;
    float pj0 = l0[j], pj1 = l1[j];
    {
        const float4* v0p = (const float4*)&l0[w * 128];
        const float4* v1p = (const float4*)&l1[w * 128];
        const float4* vdp = (const float4*)&di[w * 128];
        float a0 = 0.f, a1 = 0.f, as = 0.f;
#pragma unroll 4
        for (int g = 0; g < 32; ++g) {
            float4 v0 = v0p[g], v1 = v1p[g], vd = vdp[g];
            float dx, dy, d2, t;
            dx = pj0 - v0.x; dy = pj1 - v1.x; d2 = fmaf(dy, dy, dx * dx);
            t = (d2 <= 0.09f) ? vd.x : 0.0f;
            a0 = fmaf(t, v0.x, a0); a1 = fmaf(t, v1.x, a1); as += t;
            dx = pj0 - v0.y; dy = pj1 - v1.y; d2 = fmaf(dy, dy, dx * dx);
            t = (d2 <= 0.09f) ? vd.y : 0.0f;
            a0 = fmaf(t, v0.y, a0); a1 = fmaf(t, v1.y, a1); as += t;
            dx = pj0 - v0.z; dy = pj1 - v1.z; d2 = fmaf(dy, dy, dx * dx);
            t = (d2 <= 0.09f) ? vd.z : 0.0f;
            a0 = fmaf(t, v0.z, a0); a1 = fmaf(t, v1.z, a1); as += t;
            dx = pj0 - v0.w; dy = pj1 - v1.w; d2 = fmaf(dy, dy, dx * dx);
            t = (d2 <= 0.09f) ? vd.w : 0.0f;
            a0 = fmaf(t, v0.w, a0); a1 = fmaf(t, v1.w, a1); as += t;
        }
        r0[w * 64 + lane] = a0;
        r1[w * 64 + lane] = a1;
        r2[w * 64 + lane] = as;
    }
    __syncthreads();
    if (tid < 64) {
        float s0 = 0.f, s1 = 0.f, ss = 0.f;
#pragma unroll
        for (int kk = 0; kk < 8; ++kk) {
            s0 += r0[kk * 64 + tid];
            s1 += r1[kk * 64 + tid];
            ss += r2[kk * 64 + tid];
        }
        float dj = di[jq * 64 + tid];
        q0s[tid] = dj * s0;
        q1s[tid] = dj * s1;
        qws[tid] = dj * ss * (1.0f / NN);
    } else if (jq == 0 && tid < 128) {
        int t2 = tid - 64;
        sx1[t2] = fmaxf(mlp_p[b * MLPH + t2] + bm0[t2], 0.f);
    }
    __syncthreads();
    {   // fused h + weighted hsum partial over this block's 64 j
        int h = tid & 255, jq2 = tid >> 8;   // jq2 in {0,1}, 32 j each
        float w10 = W1[2 * h], w11 = W1[2 * h + 1], bb = b1[h];
        const float4* q0v = (const float4*)&q0s[jq2 * 32];
        const float4* q1v = (const float4*)&q1s[jq2 * 32];
        const float4* qwv = (const float4*)&qws[jq2 * 32];
        float acc = 0.f;
#pragma unroll
        for (int g = 0; g < 8; ++g) {
            float4 qa = q0v[g], qb = q1v[g], qw4 = qwv[g];
            acc = fmaf(qw4.x, fmaxf(fmaf(qb.x, w11, fmaf(qa.x, w10, bb)), 0.f), acc);
            acc = fmaf(qw4.y, fmaxf(fmaf(qb.y, w11, fmaf(qa.y, w10, bb)), 0.f), acc);
            acc = fmaf(qw4.z, fmaxf(fmaf(qb.z, w11, fmaf(qa.z, w10, bb)), 0.f), acc);
            acc = fmaf(qw4.w, fmaxf(fmaf(qb.w, w11, fmaf(qa.w, w10, bb)), 0.f), acc);
        }
        hp[jq2 * 256 + h] = acc;
    }
    __syncthreads();
    if (tid < HID) {
        r0[tid] = hp[tid] + hp[256 + tid];   // block's hs partial (r0 dead)
    } else if (jq == 0 && tid < HID + MLPH) {
        int t2 = tid - HID;
        float a = bm1[t2];
        const float* wv = Wm1 + t2 * MLPH;
#pragma unroll
        for (int k = 0; k < MLPH; ++k) a = fmaf(wv[k], sx1[k], a);
        sxf2[t2] = fmaxf(a, 0.f);
    } else if (jq == 0 && tid < HID + MLPH + 8) {
        int t2 = tid - HID - MLPH;
        float mxv = 0.f;
#pragma unroll
        for (int g = 0; g < 16; ++g) mxv = fmaxf(mxv, bmaxp[b * 16 + g]);
        float avg  = spd[b] * (1.0f / NN);
        float dens = 1.0f / sqrtf(mxv);
        sglo[t2] = fmaxf(fmaf(Wg[t2 * 2], avg, fmaf(Wg[t2 * 2 + 1], dens, bg[t2])), 0.f);
    }
    __syncthreads();
    // ---- project partial hs through E -> 8 floats, atomic fan-in ----
    {
        int o = w, ln = lane;   // 8 waves <-> 8 outputs
        const float* Eo = E + o * HID;
        float a = Eo[ln] * r0[ln];
        a = fmaf(Eo[ln + 64],  r0[ln + 64],  a);
        a = fmaf(Eo[ln + 128], r0[ln + 128], a);
        a = fmaf(Eo[ln + 192], r0[ln + 192], a);
        if (jq == 0) a = fmaf(Wp[o * CATN + ln], sxf2[ln], a);
        a = wave_sum(a);
        if (ln == 0) {
            if (jq == 0) {
                const float* wg = Wp + o * CATN + MLPH + HID;
#pragma unroll
                for (int g = 0; g < 8; ++g) a = fmaf(wg[g], sglo[g], a);
                a += cE[o] + bp[o];
            }
            atomicAdd(&out[b * OUTN + o], a);
        }
    }
}

extern "C" void kernel_launch(void* const* d_in, const int* in_sizes, int n_in,
                              void* d_out, int out_size, void* d_ws, size_t ws_size,
                              hipStream_t stream) {
    const float* x   = (const float*)d_in[0];
    const float* W1  = (const float*)d_in[1];
    const float* b1  = (const float*)d_in[2];
    const float* W2  = (const float*)d_in[3];
    const float* b2  = (const float*)d_in[4];
    const float* Wfc = (const float*)d_in[5];
    const float* bfc = (const float*)d_in[6];
    const float* Wg  = (const float*)d_in[7];
    const float* bg  = (const float*)d_in[8];
    const float* Wm0 = (const float*)d_in[9];
    const float* bm0 = (const float*)d_in[10];
    const float* Wm1 = (const float*)d_in[11];
    const float* bm1 = (const float*)d_in[12];
    const float* Wp  = (const float*)d_in[13];
    const float* bp  = (const float*)d_in[14];
    float* out = (float*)d_out;
    float* ws  = (float*)d_ws;

    float* deg   = ws;              // 32768
    float* mlp_p = ws + 32768;      // 2048
    float* bmaxp = ws + 34816;      // 512 (32 x 16)
    float* spd   = ws + 35328;      // 32
    float* E     = ws + 35360;      // 2048
    float* cE    = ws + 37408;      // 8 (+pad)
    float* pts0  = ws + 37440;      // 32768
    float* pts1  = ws + 70208;      // 32768
    // every ws cell is written before it is read each iteration -> no zero-init.

    g1<<<512, 512, 0, stream>>>(x, Wm0, W2, b2, Wfc, bfc, Wp,
                                spd, mlp_p, E, cE, deg, bmaxp, pts0, pts1, out);
    g2<<<512, 512, 0, stream>>>(pts0, pts1, deg, W1, b1, Wg, bg, Wm1, bm1,
                                Wp, bp, bm0, mlp_p, bmaxp, spd, E, cE, out);
}